// Round 1
// baseline (671.192 us; speedup 1.0000x reference)
//
#include <hip/hip_runtime.h>
#include <math.h>

// Problem constants (match reference)
constexpr int NR = 3200;
constexpr int NA = 320;
constexpr int TD = 512;
constexpr int DD = 128;
constexpr int H  = 128;
constexpr int B  = 8;
constexpr int NP = NR * NA;                     // 1,024,000 pairs
constexpr long long TOTAL = (long long)NP * H;  // 131,072,000 output elems

// ---------------- init: per-segment min/max atomic cells -----------------
__global__ void init_minmax(int* dmin_bits, int* dmax_bits) {
    int t = threadIdx.x;
    if (t < B) {
        dmin_bits[t] = 0x7F800000;        // +inf
        dmax_bits[t] = (int)0xFF800000;   // -inf
    }
}

// ---------------- small GEMM: out[N,H] = A[N,K] @ W[K,H] + bias ----------
// block = 128 threads (one per h), ROWS rows per block staged in LDS.
template<int K, int ROWS>
__global__ void gemm_rows(const float* __restrict__ A,
                          const float* __restrict__ W,
                          const float* __restrict__ bias,
                          float* __restrict__ out) {
    __shared__ float sA[ROWS * K];
    const int i0 = blockIdx.x * ROWS;
    const int h  = threadIdx.x;  // 0..127

    // cooperative, coalesced load of ROWS contiguous rows
    for (int idx = h; idx < ROWS * K; idx += H)
        sA[idx] = A[(long long)i0 * K + idx];
    __syncthreads();

    float acc[ROWS];
    const float bv = bias[h];
#pragma unroll
    for (int r = 0; r < ROWS; r++) acc[r] = bv;

#pragma unroll 4
    for (int k = 0; k < K; k++) {
        const float w = W[k * H + h];  // coalesced across threads, L2-resident
#pragma unroll
        for (int r = 0; r < ROWS; r++)
            acc[r] = fmaf(sA[r * K + k], w, acc[r]);
    }
#pragma unroll
    for (int r = 0; r < ROWS; r++)
        out[(i0 + r) * H + h] = acc[r];
}

// ---------------- distances + segment min/max --------------------------
// one block per residue i; 320 threads (5 waves), one per atom j
__global__ void dist_kernel(const float* __restrict__ tpos,
                            const float* __restrict__ dpos,
                            const int* __restrict__ seg_res,
                            const int* __restrict__ seg_atom,
                            float* __restrict__ Dbuf,
                            int* dmin_bits, int* dmax_bits) {
    const int i = blockIdx.x;
    const int j = threadIdx.x;  // 0..319
    const int sr = seg_res[i];

    const float tx = tpos[i * 3 + 0];
    const float ty = tpos[i * 3 + 1];
    const float tz = tpos[i * 3 + 2];
    const float dx = tx - dpos[j * 3 + 0];
    const float dy = ty - dpos[j * 3 + 1];
    const float dz = tz - dpos[j * 3 + 2];
    const float d  = sqrtf(dx * dx + dy * dy + dz * dz);
    Dbuf[i * NA + j] = d;

    const bool m = (sr == seg_atom[j]);
    float vmin = m ? d :  INFINITY;
    float vmax = m ? d : -INFINITY;
#pragma unroll
    for (int off = 32; off > 0; off >>= 1) {
        vmin = fminf(vmin, __shfl_down(vmin, off));
        vmax = fmaxf(vmax, __shfl_down(vmax, off));
    }
    __shared__ float smin[5], smax[5];
    const int wid  = j >> 6;
    const int lane = j & 63;
    if (lane == 0) { smin[wid] = vmin; smax[wid] = vmax; }
    __syncthreads();
    if (j == 0) {
        float mn = smin[0], mx = smax[0];
#pragma unroll
        for (int w = 1; w < 5; w++) { mn = fminf(mn, smin[w]); mx = fmaxf(mx, smax[w]); }
        // distances are >= 0, so float bit-pattern order == signed int order
        if (mn < INFINITY)  atomicMin(&dmin_bits[sr], __float_as_int(mn));
        if (mx > -INFINITY) atomicMax(&dmax_bits[sr], __float_as_int(mx));
    }
}

// ---------------- expand normalized distance in-place -------------------
// Dbuf[p] := masked ? (D - dmin)/denom (>= 0) : -1 sentinel
__global__ void dnorm_kernel(float* __restrict__ Dbuf,
                             const int* __restrict__ seg_res,
                             const int* __restrict__ seg_atom,
                             const int* __restrict__ dmin_bits,
                             const int* __restrict__ dmax_bits) {
    const int p = blockIdx.x * blockDim.x + threadIdx.x;
    if (p >= NP) return;
    const int i = p / NA;
    const int j = p - i * NA;
    float outv = -1.0f;
    const int sr = seg_res[i];
    if (sr == seg_atom[j]) {
        const int mnb = dmin_bits[sr];
        const int mxb = dmax_bits[sr];
        const float dmin = (mnb == 0x7F800000) ? 0.0f : __int_as_float(mnb);
        const float dmax = (mxb == (int)0xFF800000) ? 1.0f : __int_as_float(mxb);
        const float denom = (dmax > dmin) ? (dmax - dmin) : 1.0f;
        outv = (Dbuf[p] - dmin) / denom;
    }
    Dbuf[p] = outv;
}

// ---------------- fast tanh --------------------------------------------
__device__ __forceinline__ float fast_tanh(float x) {
    const float cx = fminf(fmaxf(x, -15.0f), 15.0f);
    const float e  = __expf(2.0f * cx);
    return 1.0f - __fdividef(2.0f, e + 1.0f);
}

// ---------------- the 524 MB writer -------------------------------------
// thread -> 4 consecutive h elements (float4); H=128 divisible by 4 so a
// thread never crosses a (i,j) pair boundary.
__global__ void final_kernel(const float* __restrict__ tf,
                             const float* __restrict__ df,
                             const float* __restrict__ dnorm,
                             float* __restrict__ out) {
    const long long t    = (long long)blockIdx.x * blockDim.x + threadIdx.x;
    const long long base = t * 4;
    if (base >= TOTAL) return;
    const int p = (int)(base >> 7);   // pair index
    const int h = (int)(base & 127);  // h offset
    const float dn = dnorm[p];
    float4 o;
    if (dn >= 0.0f) {
        const int i = p / NA;
        const int j = p - i * NA;
        const float4 tv = *(const float4*)(tf + i * H + h);
        const float4 dv = *(const float4*)(df + j * H + h);
        o.x = fast_tanh(tv.x - dv.x + dn);
        o.y = fast_tanh(tv.y - dv.y + dn);
        o.z = fast_tanh(tv.z - dv.z + dn);
        o.w = fast_tanh(tv.w - dv.w + dn);
    } else {
        o.x = 0.0f; o.y = 0.0f; o.z = 0.0f; o.w = 0.0f;
    }
    *(float4*)(out + base) = o;
}

extern "C" void kernel_launch(void* const* d_in, const int* in_sizes, int n_in,
                              void* d_out, int out_size, void* d_ws, size_t ws_size,
                              hipStream_t stream) {
    const float* target_feature = (const float*)d_in[0];  // [NR, TD]
    const float* drug_feature   = (const float*)d_in[1];  // [NA, DD]
    const float* target_pos     = (const float*)d_in[2];  // [NR, 3]
    const float* drug_pos       = (const float*)d_in[3];  // [NA, 3]
    const float* Wt             = (const float*)d_in[4];  // [TD, H]
    const float* bt             = (const float*)d_in[5];  // [H]
    const float* Wd             = (const float*)d_in[6];  // [DD, H]
    const float* bd             = (const float*)d_in[7];  // [H]
    const int*   seg_res        = (const int*)d_in[8];    // [NR]
    const int*   seg_atom       = (const int*)d_in[9];    // [NA]
    float* out = (float*)d_out;

    // workspace layout (floats): tf | df | Dbuf | dmin_bits | dmax_bits
    float* ws   = (float*)d_ws;
    float* tf   = ws;               // NR*H   = 409,600
    float* df   = tf + NR * H;      // NA*H   =  40,960
    float* Dbuf = df + NA * H;      // NP     = 1,024,000
    int*   dmin_bits = (int*)(Dbuf + NP);  // B
    int*   dmax_bits = dmin_bits + B;      // B

    init_minmax<<<1, 64, 0, stream>>>(dmin_bits, dmax_bits);
    gemm_rows<TD, 4><<<NR / 4, H, 0, stream>>>(target_feature, Wt, bt, tf);
    gemm_rows<DD, 4><<<NA / 4, H, 0, stream>>>(drug_feature, Wd, bd, df);
    dist_kernel<<<NR, NA, 0, stream>>>(target_pos, drug_pos, seg_res, seg_atom,
                                       Dbuf, dmin_bits, dmax_bits);
    dnorm_kernel<<<(NP + 255) / 256, 256, 0, stream>>>(Dbuf, seg_res, seg_atom,
                                                       dmin_bits, dmax_bits);
    final_kernel<<<(int)(TOTAL / 4 / 256), 256, 0, stream>>>(tf, df, Dbuf, out);
}

// Round 2
// 632.781 us; speedup vs baseline: 1.0607x; 1.0607x over previous
//
#include <hip/hip_runtime.h>
#include <math.h>

// Problem constants (match reference)
constexpr int NR = 3200;
constexpr int NA = 320;
constexpr int TD = 512;
constexpr int DD = 128;
constexpr int H  = 128;
constexpr int B  = 8;
constexpr int NP = NR * NA;                     // 1,024,000 pairs
constexpr long long TOTAL = (long long)NP * H;  // 131,072,000 output elems

typedef float f4 __attribute__((ext_vector_type(4)));

// ---------------- small GEMM: out[N,H] = A[N,K] @ W[K,H] + bias ----------
// block = 256 threads: h = t&127 (output column), half = t>>7 (k-split).
// ROWS rows per block staged in LDS. Optionally initializes the segment
// min/max atomic cells from block 0 (saves a separate init launch).
template<int K, int ROWS>
__global__ __launch_bounds__(256) void gemm_rows(const float* __restrict__ A,
                                                 const float* __restrict__ W,
                                                 const float* __restrict__ bias,
                                                 float* __restrict__ out,
                                                 int* dmin_bits, int* dmax_bits) {
    __shared__ float sA[ROWS * K];
    __shared__ float sAcc[ROWS * H];
    const int t    = threadIdx.x;
    const int h    = t & (H - 1);
    const int half = t >> 7;
    const int i0   = blockIdx.x * ROWS;

    if (dmin_bits != nullptr && blockIdx.x == 0 && t < B) {
        dmin_bits[t] = 0x7F800000;        // +inf
        dmax_bits[t] = (int)0xFF800000;   // -inf
    }

    // cooperative, coalesced load of ROWS contiguous rows
    for (int idx = t; idx < ROWS * K; idx += 256)
        sA[idx] = A[i0 * K + idx];
    __syncthreads();

    float acc[ROWS];
#pragma unroll
    for (int r = 0; r < ROWS; r++) acc[r] = 0.0f;

    const int k0 = half * (K / 2);
    const int k1 = k0 + (K / 2);
#pragma unroll 4
    for (int k = k0; k < k1; k++) {
        const float w = W[k * H + h];  // coalesced, L2-resident
#pragma unroll
        for (int r = 0; r < ROWS; r++)
            acc[r] = fmaf(sA[r * K + k], w, acc[r]);
    }

    if (half == 1) {
#pragma unroll
        for (int r = 0; r < ROWS; r++) sAcc[r * H + h] = acc[r];
    }
    __syncthreads();
    if (half == 0) {
        const float bv = bias[h];
#pragma unroll
        for (int r = 0; r < ROWS; r++)
            out[(i0 + r) * H + h] = acc[r] + sAcc[r * H + h] + bv;
    }
}

// ---------------- distances + segment min/max --------------------------
// one block per residue i; 320 threads (5 waves), one per atom j
__global__ void dist_kernel(const float* __restrict__ tpos,
                            const float* __restrict__ dpos,
                            const int* __restrict__ seg_res,
                            const int* __restrict__ seg_atom,
                            float* __restrict__ Dbuf,
                            int* dmin_bits, int* dmax_bits) {
    const int i = blockIdx.x;
    const int j = threadIdx.x;  // 0..319
    const int sr = seg_res[i];

    const float tx = tpos[i * 3 + 0];
    const float ty = tpos[i * 3 + 1];
    const float tz = tpos[i * 3 + 2];
    const float dx = tx - dpos[j * 3 + 0];
    const float dy = ty - dpos[j * 3 + 1];
    const float dz = tz - dpos[j * 3 + 2];
    const float d  = sqrtf(dx * dx + dy * dy + dz * dz);
    Dbuf[i * NA + j] = d;

    const bool m = (sr == seg_atom[j]);
    float vmin = m ? d :  INFINITY;
    float vmax = m ? d : -INFINITY;
#pragma unroll
    for (int off = 32; off > 0; off >>= 1) {
        vmin = fminf(vmin, __shfl_down(vmin, off));
        vmax = fmaxf(vmax, __shfl_down(vmax, off));
    }
    __shared__ float smin[5], smax[5];
    const int wid  = j >> 6;
    const int lane = j & 63;
    if (lane == 0) { smin[wid] = vmin; smax[wid] = vmax; }
    __syncthreads();
    if (j == 0) {
        float mn = smin[0], mx = smax[0];
#pragma unroll
        for (int w = 1; w < 5; w++) { mn = fminf(mn, smin[w]); mx = fmaxf(mx, smax[w]); }
        // distances are >= 0, so float bit-pattern order == signed int order
        if (mn < INFINITY)  atomicMin(&dmin_bits[sr], __float_as_int(mn));
        if (mx > -INFINITY) atomicMax(&dmax_bits[sr], __float_as_int(mx));
    }
}

// ---------------- per-segment {dmin, 1/denom} --------------------------
__global__ void finalize_params(const int* __restrict__ dmin_bits,
                                const int* __restrict__ dmax_bits,
                                float2* __restrict__ params) {
    const int s = threadIdx.x;
    if (s < B) {
        const int mnb = dmin_bits[s];
        const int mxb = dmax_bits[s];
        const float dmin = (mnb == 0x7F800000) ? 0.0f : __int_as_float(mnb);
        const float dmax = (mxb == (int)0xFF800000) ? 1.0f : __int_as_float(mxb);
        const float denom = (dmax > dmin) ? (dmax - dmin) : 1.0f;
        params[s] = make_float2(dmin, 1.0f / denom);
    }
}

// ---------------- fast tanh --------------------------------------------
__device__ __forceinline__ float fast_tanh(float x) {
    const float cx = fminf(fmaxf(x, -15.0f), 15.0f);
    const float e  = __expf(2.0f * cx);
    return 1.0f - __fdividef(2.0f, e + 1.0f);
}

// ---------------- the 524 MB writer -------------------------------------
// thread -> 4 consecutive h elements (float4). Recomputes dnorm from the
// raw distance + per-segment params (kills the separate dnorm pass).
// Nontemporal stores keep tf/df/Dbuf resident in L2.
__global__ __launch_bounds__(256) void final_kernel(const float* __restrict__ tf,
                                                    const float* __restrict__ df,
                                                    const float* __restrict__ Dbuf,
                                                    const int* __restrict__ seg_res,
                                                    const int* __restrict__ seg_atom,
                                                    const float2* __restrict__ params,
                                                    float* __restrict__ out) {
    const int t    = blockIdx.x * 256 + threadIdx.x;  // < 32,768,000
    const int base = t << 2;                          // element idx < 131,072,000
    const int p    = base >> 7;                       // pair index
    const int h    = base & 127;                      // h offset
    const int i    = p / NA;
    const int j    = p - i * NA;

    f4 o = {0.0f, 0.0f, 0.0f, 0.0f};
    const int sr = seg_res[i];
    if (sr == seg_atom[j]) {
        const float2 pp = params[sr];
        const float  dn = (Dbuf[p] - pp.x) * pp.y;
        const f4 tv = *(const f4*)(tf + i * H + h);
        const f4 dv = *(const f4*)(df + j * H + h);
        o.x = fast_tanh(tv.x - dv.x + dn);
        o.y = fast_tanh(tv.y - dv.y + dn);
        o.z = fast_tanh(tv.z - dv.z + dn);
        o.w = fast_tanh(tv.w - dv.w + dn);
    }
    __builtin_nontemporal_store(o, (f4*)(out + base));
}

extern "C" void kernel_launch(void* const* d_in, const int* in_sizes, int n_in,
                              void* d_out, int out_size, void* d_ws, size_t ws_size,
                              hipStream_t stream) {
    const float* target_feature = (const float*)d_in[0];  // [NR, TD]
    const float* drug_feature   = (const float*)d_in[1];  // [NA, DD]
    const float* target_pos     = (const float*)d_in[2];  // [NR, 3]
    const float* drug_pos       = (const float*)d_in[3];  // [NA, 3]
    const float* Wt             = (const float*)d_in[4];  // [TD, H]
    const float* bt             = (const float*)d_in[5];  // [H]
    const float* Wd             = (const float*)d_in[6];  // [DD, H]
    const float* bd             = (const float*)d_in[7];  // [H]
    const int*   seg_res        = (const int*)d_in[8];    // [NR]
    const int*   seg_atom       = (const int*)d_in[9];    // [NA]
    float* out = (float*)d_out;

    // workspace layout (floats): tf | df | Dbuf | dmin_bits | dmax_bits | params
    float* ws   = (float*)d_ws;
    float* tf   = ws;               // NR*H   = 409,600
    float* df   = tf + NR * H;      // NA*H   =  40,960
    float* Dbuf = df + NA * H;      // NP     = 1,024,000
    int*    dmin_bits = (int*)(Dbuf + NP);      // B
    int*    dmax_bits = dmin_bits + B;          // B
    float2* params    = (float2*)(dmax_bits + B);

    gemm_rows<TD, 4><<<NR / 4, 256, 0, stream>>>(target_feature, Wt, bt, tf,
                                                 dmin_bits, dmax_bits);
    gemm_rows<DD, 4><<<NA / 4, 256, 0, stream>>>(drug_feature, Wd, bd, df,
                                                 nullptr, nullptr);
    dist_kernel<<<NR, NA, 0, stream>>>(target_pos, drug_pos, seg_res, seg_atom,
                                       Dbuf, dmin_bits, dmax_bits);
    finalize_params<<<1, 64, 0, stream>>>(dmin_bits, dmax_bits, params);
    final_kernel<<<(int)(TOTAL / 4 / 256), 256, 0, stream>>>(tf, df, Dbuf, seg_res,
                                                             seg_atom, params, out);
}